// Round 3
// baseline (492.229 us; speedup 1.0000x reference)
//
#include <hip/hip_runtime.h>
#include <cstdint>

typedef unsigned short u16;
typedef unsigned long long u64;
typedef __attribute__((ext_vector_type(8))) short bf16x8;
typedef __attribute__((ext_vector_type(4))) float f32x4;

__device__ __forceinline__ u16 f2b(float f){
  union { float f; uint32_t i; } v; v.f = f;
  uint32_t r = v.i + 0x7FFFu + ((v.i >> 16) & 1u);   // RNE
  return (u16)(r >> 16);
}
__device__ __forceinline__ float b2f(u16 u){
  union { uint32_t i; float f; } v; v.i = ((uint32_t)u) << 16; return v.f;
}
__device__ __forceinline__ float sigmoidf(float x){ return 1.0f / (1.0f + __expf(-x)); }

#define MFMA16(a,b,c) __builtin_amdgcn_mfma_f32_16x16x32_bf16(a,b,c,0,0,0)

// ---- K0: build wT (transposed, bf16 hi/lo split) of allw = concat(w0,w1).
// wT[b][d][k], k in allw space (0..4095). hi = bf16(w), lo = bf16(w - hi).
__global__ __launch_bounds__(256) void k_prep(
    const float* __restrict__ w0, const float* __restrict__ w1,
    u16* __restrict__ wThi, u16* __restrict__ wTlo){
  __shared__ float tile[64][65];
  int tid = threadIdx.x;
  int t = blockIdx.x;                       // 0..127
  int b = t >> 6, kt = t & 63;
  int k0 = kt * 64;
  const float* src = (k0 < 2048) ? (w0 + ((size_t)b*2048 + k0)*64)
                                 : (w1 + ((size_t)b*2048 + (k0 - 2048))*64);
  int r0 = tid >> 6, c = tid & 63;
  #pragma unroll
  for (int it = 0; it < 16; ++it){
    int n = it*4 + r0;
    tile[n][c] = src[(size_t)n*64 + c];
  }
  __syncthreads();
  #pragma unroll
  for (int it = 0; it < 16; ++it){
    int d = it*4 + r0;
    float v = tile[c][d];
    u16 h = f2b(v);
    float lo = v - b2f(h);
    size_t o = ((size_t)b*64 + d)*4096 + k0 + c;
    wThi[o] = h;
    wTlo[o] = f2b(lo);
  }
}

// ---- K1: mask-streaming MFMA GEMM. psum[row,:] = sum_j mask[row,j]*w[j,:].
// A = on-the-fly bf16 0/1 mask tile (streamed once at full BW, pure register
// pipeline, no LDS, no gathers). B = wThi/wTlo from L2. Deg via ones-MFMA.
// blocks 0..511: big (ww&wem), 64 rows x K=1024 each (4 k-chunks/row).
// blocks 512..767: dep (d0/d1), 64 rows x K=1024 (2 k-halves).
// blocks 768..1023: bitOp; 1024..1039: weight packing; 1040: ghat.
__global__ __launch_bounds__(256) void k_mask(
    const float* __restrict__ ww, const float* __restrict__ wem,
    const float* __restrict__ d0, const float* __restrict__ d1,
    const float* __restrict__ wes, const float* __restrict__ wop,
    const u16* __restrict__ wThi, const u16* __restrict__ wTlo,
    const float* __restrict__ nh, const float* __restrict__ Wg, const float* __restrict__ bg,
    const float* __restrict__ Wf, const float* __restrict__ Wupd, const float* __restrict__ Wo,
    u16* __restrict__ psumB, int* __restrict__ pcntB,
    u16* __restrict__ psumD, int* __restrict__ pcntD,
    u64* __restrict__ bitOp, float* __restrict__ ghat,
    uint32_t* __restrict__ pkWf, uint32_t* __restrict__ pkWu, uint32_t* __restrict__ pkWo){
  int tid = threadIdx.x, wave = tid >> 6, lane = tid & 63;
  int bid = blockIdx.x;
  if (bid >= 768){
    if (bid >= 1024){
      int aux = bid - 1024;                        // 0..16
      if (aux == 16){                              // ghat
        if (tid < 128){
          int b = tid >> 6, h = tid & 63;
          float g = bg[h];
          for (int d = 0; d < 64; ++d) g += nh[b*64 + d] * Wg[d*64 + h];
          float ss = g * g;
          #pragma unroll
          for (int o = 32; o > 0; o >>= 1) ss += __shfl_xor(ss, o, 64);
          ghat[b*64 + h] = g / (sqrtf(ss) + 1e-30f);
        }
        return;
      }
      for (int k = tid; k < 1024; k += 256){       // bf16-pair weight packing
        int i = aux*1024 + k;                      // 0..16383
        const float* src; uint32_t* dst; int li;
        if (i < 8192){ src = Wf; dst = pkWf; li = i; }
        else if (i < 14336){ src = Wupd; dst = pkWu; li = i - 8192; }
        else { src = Wo; dst = pkWo; li = i - 14336; }
        int k2 = li >> 6, ln = li & 63;
        dst[li] = (uint32_t)f2b(src[(2*k2)*64 + ln]) | ((uint32_t)f2b(src[(2*k2+1)*64 + ln]) << 16);
      }
      return;
    }
    // wop bits: wes & wop -> bitOp[n][o>>6]
    int w = (bid - 768)*4 + wave;                  // 0..1023
    int ng0 = w * 8;
    #pragma unroll
    for (int i = 0; i < 8; ++i){
      int n = ng0 + i;
      float vx = wop[(size_t)n*128 + lane];
      float vy = wop[(size_t)n*128 + 64 + lane];
      float e  = wes[n];
      u64 m0 = __ballot((e != 0.f) && (vx != 0.f));
      u64 m1 = __ballot((e != 0.f) && (vy != 0.f));
      if (lane == 0) bitOp[(size_t)n*2]     = m0;
      if (lane == 1) bitOp[(size_t)n*2 + 1] = m1;
    }
    return;
  }
  // ---- GEMM setup (all wave-uniform except lane decomposition)
  bool big; int wb, kOffW, tBase, tStride;
  const float *mArow, *mBrow; size_t ldm;
  u16* psArr; int* pcArr;
  if (bid < 512){
    int rowblk = bid >> 2, kq = bid & 3;
    int bb = rowblk >> 6;
    int grow = bb*4096 + (rowblk & 63)*64 + wave*16;   // global row 0..8191
    mArow = ww  + (size_t)grow*4096 + kq*1024;
    mBrow = wem + (size_t)grow*4096 + kq*1024;
    ldm = 4096; big = true;
    wb = bb; kOffW = kq*1024;
    tBase = grow*4 + kq; tStride = 4;
    psArr = psumB; pcArr = pcntB;
  } else {
    int i = bid - 512;
    int inst = i >> 6, r6 = i & 63;                    // inst: d0b0,d0b1,d1b0,d1b1
    int rowblkL = r6 >> 1, kh = r6 & 1;
    int prow = inst*2048 + rowblkL*64 + wave*16;       // psumD row space 0..8191
    const float* marr = (inst < 2) ? d0 : d1;
    int mrow = (inst < 2) ? prow : (prow - 4096);
    mArow = marr + (size_t)mrow*2048 + kh*1024;
    mBrow = mArow; ldm = 2048; big = false;
    wb = inst & 1; kOffW = ((inst >= 2) ? 2048 : 0) + kh*1024;
    tBase = prow*2 + kh; tStride = 2;
    psArr = psumD; pcArr = pcntD;
  }
  int col = lane & 15, oct = lane >> 4;
  const float* pa = mArow + (size_t)col*ldm + oct*8;   // A: mask row = col
  const float* pc = mBrow + (size_t)col*ldm + oct*8;
  const u16* ph = wThi + ((size_t)wb*64 + col)*4096 + kOffW + oct*8;  // B: d = n*16+col
  const u16* pl = wTlo + ((size_t)wb*64 + col)*4096 + kOffW + oct*8;

  f32x4 acc0 = {0.f,0.f,0.f,0.f}, acc1 = acc0, acc2 = acc0, acc3 = acc0, accD = acc0;
  union { uint32_t w[4]; bf16x8 v; } onesU;
  onesU.w[0] = onesU.w[1] = onesU.w[2] = onesU.w[3] = 0x3F803F80u;   // bf16 1.0 x8
  bf16x8 ones = onesU.v;

  // prefetch step 0
  float4 a0 = *(const float4*)pa;
  float4 a1 = *(const float4*)(pa + 4);
  float4 c0v = {0,0,0,0}, c1v = {0,0,0,0};
  if (big){ c0v = *(const float4*)pc; c1v = *(const float4*)(pc + 4); }
  bf16x8 h0 = *(const bf16x8*)ph;
  bf16x8 h1 = *(const bf16x8*)(ph + 65536);
  bf16x8 h2 = *(const bf16x8*)(ph + 131072);
  bf16x8 h3 = *(const bf16x8*)(ph + 196608);
  bf16x8 l0 = *(const bf16x8*)pl;
  bf16x8 l1 = *(const bf16x8*)(pl + 65536);
  bf16x8 l2 = *(const bf16x8*)(pl + 131072);
  bf16x8 l3 = *(const bf16x8*)(pl + 196608);

  #pragma unroll 1
  for (int s = 0; s < 32; ++s){
    float4 wa0 = a0, wa1 = a1, wc0 = c0v, wc1 = c1v;
    bf16x8 bh0 = h0, bh1 = h1, bh2 = h2, bh3 = h3;
    bf16x8 bl0 = l0, bl1 = l1, bl2 = l2, bl3 = l3;
    if (s < 31){                                   // issue next-step loads now
      const float* qa = pa + (size_t)(s+1)*32;
      a0 = *(const float4*)qa; a1 = *(const float4*)(qa + 4);
      if (big){
        const float* qc = pc + (size_t)(s+1)*32;
        c0v = *(const float4*)qc; c1v = *(const float4*)(qc + 4);
      }
      const u16* qh = ph + (size_t)(s+1)*32;
      h0 = *(const bf16x8*)qh;
      h1 = *(const bf16x8*)(qh + 65536);
      h2 = *(const bf16x8*)(qh + 131072);
      h3 = *(const bf16x8*)(qh + 196608);
      const u16* ql = pl + (size_t)(s+1)*32;
      l0 = *(const bf16x8*)ql;
      l1 = *(const bf16x8*)(ql + 65536);
      l2 = *(const bf16x8*)(ql + 131072);
      l3 = *(const bf16x8*)(ql + 196608);
    }
    // build A fragment: bf16 1.0/0.0 mask, 8 consecutive k per lane
#define SEL(x,y) ((x != 0.f) && (!big || (y != 0.f)))
    union { uint32_t w[4]; bf16x8 v; } af;
    af.w[0] = (SEL(wa0.x,wc0.x)?0x3F80u:0u) | (SEL(wa0.y,wc0.y)?0x3F800000u:0u);
    af.w[1] = (SEL(wa0.z,wc0.z)?0x3F80u:0u) | (SEL(wa0.w,wc0.w)?0x3F800000u:0u);
    af.w[2] = (SEL(wa1.x,wc1.x)?0x3F80u:0u) | (SEL(wa1.y,wc1.y)?0x3F800000u:0u);
    af.w[3] = (SEL(wa1.z,wc1.z)?0x3F80u:0u) | (SEL(wa1.w,wc1.w)?0x3F800000u:0u);
#undef SEL
    bf16x8 a = af.v;
    acc0 = MFMA16(a, bh0, acc0);
    acc0 = MFMA16(a, bl0, acc0);
    acc1 = MFMA16(a, bh1, acc1);
    acc1 = MFMA16(a, bl1, acc1);
    acc2 = MFMA16(a, bh2, acc2);
    acc2 = MFMA16(a, bl2, acc2);
    acc3 = MFMA16(a, bh3, acc3);
    acc3 = MFMA16(a, bl3, acc3);
    accD = MFMA16(a, ones, accD);
  }
  // ---- write psum (bf16) + deg counts. D: row=oct*4+r, col=lane&15.
  #pragma unroll
  for (int r = 0; r < 4; ++r){
    size_t t = (size_t)tBase + (size_t)(oct*4 + r) * tStride;
    u16* prow = psArr + t*64;
    prow[ 0 + col] = f2b(acc0[r]);
    prow[16 + col] = f2b(acc1[r]);
    prow[32 + col] = f2b(acc2[r]);
    prow[48 + col] = f2b(acc3[r]);
    if (col == 0) pcArr[t] = (int)(accD[r] + 0.5f);
  }
}

// ---- K2: combine partials + linear transform + c*bias + l2n (unchanged)
__global__ __launch_bounds__(256) void k_fin(
    const u16* __restrict__ psumB, const int* __restrict__ pcntB,
    const u16* __restrict__ psumD, const int* __restrict__ pcntD,
    const float* __restrict__ Wwk, const float* __restrict__ bwk,
    const float* __restrict__ Wws, const float* __restrict__ bws,
    u16* __restrict__ wwkn, u16* __restrict__ wwsn){
  __shared__ float sWk[4096], sWs[4096];
  int tid = threadIdx.x, lane = tid & 63, wave = tid >> 6;
  for (int i = tid; i < 1024; i += 256){
    ((float4*)sWk)[i] = ((const float4*)Wwk)[i];
    ((float4*)sWs)[i] = ((const float4*)Wws)[i];
  }
  __syncthreads();
  for (int r = 0; r < 4; ++r){
    int wid = blockIdx.x*4 + wave + r*4096;        // 0..16383
    float S; float y; const float* sW; u16* outp; size_t oidx;
    if (wid < 8192){                               // big rows (word_w_k)
      S = b2f(psumB[((size_t)wid*4 + 0)*64 + lane]) + b2f(psumB[((size_t)wid*4 + 1)*64 + lane])
        + b2f(psumB[((size_t)wid*4 + 2)*64 + lane]) + b2f(psumB[((size_t)wid*4 + 3)*64 + lane]);
      int T = pcntB[wid*4] + pcntB[wid*4 + 1] + pcntB[wid*4 + 2] + pcntB[wid*4 + 3];
      y = (float)T * bwk[lane]; sW = sWk; outp = wwkn; oidx = wid;
    } else {                                       // dep rows (word_w_s)
      int rp = wid - 8192;
      S = b2f(psumD[((size_t)rp*2 + 0)*64 + lane]) + b2f(psumD[((size_t)rp*2 + 1)*64 + lane]);
      int T = pcntD[rp*2] + pcntD[rp*2 + 1];
      y = (float)T * bws[lane]; sW = sWs; outp = wwsn;
      int b, n;
      if (rp < 4096){ b = rp >> 11; n = rp & 2047; }
      else { int rr = rp - 4096; b = rr >> 11; n = 2048 + (rr & 2047); }
      oidx = (size_t)b*4096 + n;
    }
    #pragma unroll 8
    for (int d = 0; d < 64; ++d) y += __shfl(S, d, 64) * sW[d*64 + lane];
    float ss = y * y;
    #pragma unroll
    for (int o = 32; o > 0; o >>= 1) ss += __shfl_xor(ss, o, 64);
    outp[oidx*64 + lane] = f2b(y / (sqrtf(ss) + 1e-30f));
  }
}

// ---- K3: gate + update + Wo projection (unchanged)
__global__ __launch_bounds__(256, 2) void k_update(
    const float* __restrict__ w0, const float* __restrict__ w1,
    const float* __restrict__ gw, const float* __restrict__ ghat,
    const u16* __restrict__ wwkn, const u16* __restrict__ wwsn,
    const uint32_t* __restrict__ pkWf, const uint32_t* __restrict__ pkWu,
    const uint32_t* __restrict__ pkWo,
    const float* __restrict__ bf, const float* __restrict__ bupd, const float* __restrict__ bo,
    float* __restrict__ out, float* __restrict__ WUo){
  __shared__ uint32_t pWf[8192];    // 32 KB
  __shared__ uint32_t pWu[6144];    // 24 KB
  __shared__ uint32_t pWo[2048];    // 8 KB
  __shared__ float xsh[4][256];     // 4 KB
  int tid = threadIdx.x;
  for (int i = tid; i < 2048; i += 256) ((uint4*)pWf)[i] = ((const uint4*)pkWf)[i];
  for (int i = tid; i < 1536; i += 256) ((uint4*)pWu)[i] = ((const uint4*)pkWu)[i];
  for (int i = tid; i < 512;  i += 256) ((uint4*)pWo)[i] = ((const uint4*)pkWo)[i];
  __syncthreads();
  int lane = tid & 63, wave = tid >> 6;
  float bff = bf[lane], bup = bupd[lane], boo = bo[lane];
  float aw[4], wgv[4], wk[4], wsv[4];
  #pragma unroll
  for (int t = 0; t < 4; ++t){
    int row = blockIdx.x*4 + wave + t*2048;
    int b = row >> 12, n = row & 4095;
    aw[t] = (n < 2048) ? w0[((size_t)(b*2048 + n))*64 + lane]
                       : w1[((size_t)(b*2048 + n - 2048))*64 + lane];
    float gvv = gw[b*4096 + n];
    wgv[t] = (gvv != 0.f) ? ghat[b*64 + lane] : 0.f;
    wk[t]  = b2f(wwkn[(size_t)row*64 + lane]);
    wsv[t] = b2f(wwsn[(size_t)row*64 + lane]);
  }
  #pragma unroll
  for (int t = 0; t < 4; ++t){
    int row = blockIdx.x*4 + wave + t*2048;
    int b = row >> 12, n = row & 4095;
    xsh[wave][lane] = aw[t]; xsh[wave][64 + lane] = wgv[t];
    xsh[wave][128 + lane] = wk[t]; xsh[wave][192 + lane] = wsv[t];
    float f = bff, u = bup;
    #pragma unroll 8
    for (int k2 = 0; k2 < 32; ++k2){
      float2 xv = *(const float2*)&xsh[wave][2*k2];
      uint32_t wf = pWf[k2*64 + lane];
      f += xv.x * b2f((u16)wf) + xv.y * b2f((u16)(wf >> 16));
    }
    #pragma unroll 8
    for (int k2 = 32; k2 < 128; ++k2){
      float2 xv = *(const float2*)&xsh[wave][2*k2];
      uint32_t wf = pWf[k2*64 + lane];
      uint32_t wu = pWu[(k2 - 32)*64 + lane];
      f += xv.x * b2f((u16)wf) + xv.y * b2f((u16)(wf >> 16));
      u += xv.x * b2f((u16)wu) + xv.y * b2f((u16)(wu >> 16));
    }
    f = sigmoidf(f);
    u = fmaxf(u, 0.f);
    float wu = fmaxf(f, 0.2f) * aw[t] + (1.f - f) * u;
    out[((size_t)b*4224 + n)*64 + lane] = wu;
    float o = boo;
    #pragma unroll 8
    for (int k2 = 0; k2 < 32; ++k2){
      uint32_t wo2 = pWo[k2*64 + lane];
      o += __shfl(wu, 2*k2, 64) * b2f((u16)wo2) + __shfl(wu, 2*k2 + 1, 64) * b2f((u16)(wo2 >> 16));
    }
    WUo[(size_t)row*64 + lane] = o;
  }
}

// ---- K4: fused op aggregation + epilogue (unchanged). One block per (b,o).
__global__ __launch_bounds__(256) void k_opfin(
    const u64* __restrict__ bitOp, const float* __restrict__ WUo,
    const float* __restrict__ opE,
    const float* __restrict__ Wf2, const float* __restrict__ bf2,
    const float* __restrict__ Wout, const float* __restrict__ bout,
    float* __restrict__ out){
  __shared__ float sW2[8192];   // 32 KB
  __shared__ float sWo[4096];   // 16 KB
  __shared__ int q[4][96];
  __shared__ float sacc[4][64];
  __shared__ int scnt[4];
  __shared__ float xsh[128];
  int tid = threadIdx.x, lane = tid & 63, wave = tid >> 6;
  for (int i = tid; i < 2048; i += 256) ((float4*)sW2)[i] = ((const float4*)Wf2)[i];
  for (int i = tid; i < 1024; i += 256) ((float4*)sWo)[i] = ((const float4*)Wout)[i];
  int rowIdx = blockIdx.x;                      // b*128 + o
  int b = rowIdx >> 7, o = rowIdx & 127;
  int wrd = o >> 6, bit = o & 63;
  const u64* bp = bitOp + (size_t)b*8192 + (size_t)wave*2048 + wrd;
  u64 lt = (1ULL << lane) - 1ULL;
  u64 vv[16];
  #pragma unroll
  for (int it = 0; it < 16; ++it) vv[it] = bp[(size_t)(it*64 + lane)*2];
  int cnt = 0;
  #pragma unroll
  for (int it = 0; it < 16; ++it){
    bool nz = (vv[it] >> bit) & 1ULL;
    u64 m = __ballot(nz);
    if (nz) q[wave][cnt + (int)__popcll(m & lt)] = wave*1024 + it*64 + lane;
    cnt += (int)__popcll(m);
  }
  const float* Xb = WUo + (size_t)b*4096*64 + lane;
  float acc = 0.f;
  int i = 0;
  for (; i + 8 <= cnt; i += 8){
    int4 c0 = *(const int4*)&q[wave][i];
    int4 c1 = *(const int4*)&q[wave][i + 4];
    float v0 = Xb[(size_t)c0.x*64], v1 = Xb[(size_t)c0.y*64];
    float v2 = Xb[(size_t)c0.z*64], v3 = Xb[(size_t)c0.w*64];
    float v4 = Xb[(size_t)c1.x*64], v5 = Xb[(size_t)c1.y*64];
    float v6 = Xb[(size_t)c1.z*64], v7 = Xb[(size_t)c1.w*64];
    acc += ((v0 + v1) + (v2 + v3)) + ((v4 + v5) + (v6 + v7));
  }
  for (; i < cnt; ++i) acc += Xb[(size_t)q[wave][i]*64];
  sacc[wave][lane] = acc;
  if (lane == 0) scnt[wave] = cnt;
  __syncthreads();
  if (wave == 0){
    float t = sacc[0][lane] + sacc[1][lane] + sacc[2][lane] + sacc[3][lane];
    float deg = (float)(scnt[0] + scnt[1] + scnt[2] + scnt[3]);
    float wo = t / (deg + 1e-30f);
    float e  = opE[(size_t)rowIdx*64 + lane];
    xsh[lane] = e; xsh[64 + lane] = wo;
    float f = bf2[lane], u = bout[lane];
    #pragma unroll 8
    for (int k = 0; k < 128; ++k) f += xsh[k] * sW2[k*64 + lane];
    #pragma unroll 8
    for (int d = 0; d < 64; ++d)  u += xsh[64 + d] * sWo[d*64 + lane];
    f = sigmoidf(f);
    u = fmaxf(u, 0.f);
    float res = fmaxf(f, 0.2f) * e + (1.f - f) * u;
    out[((size_t)b*4224 + 4096 + o)*64 + lane] = res;
  }
}

extern "C" void kernel_launch(void* const* d_in, const int* in_sizes, int n_in,
                              void* d_out, int out_size, void* d_ws, size_t ws_size,
                              hipStream_t stream){
  const float* w0   = (const float*)d_in[0];
  const float* w1   = (const float*)d_in[1];
  const float* nh   = (const float*)d_in[2];
  const float* opE  = (const float*)d_in[3];
  const float* wes  = (const float*)d_in[4];
  const float* wem  = (const float*)d_in[5];
  const float* wop  = (const float*)d_in[6];
  const float* ww   = (const float*)d_in[7];
  const float* d0   = (const float*)d_in[8];
  const float* d1   = (const float*)d_in[9];
  const float* gw   = (const float*)d_in[10];
  const float* Wg   = (const float*)d_in[11];
  const float* bg   = (const float*)d_in[12];
  const float* Wwk  = (const float*)d_in[13];
  const float* bwk  = (const float*)d_in[14];
  const float* Wws  = (const float*)d_in[15];
  const float* bws  = (const float*)d_in[16];
  const float* Wo   = (const float*)d_in[17];
  const float* bo   = (const float*)d_in[18];
  const float* Wupd = (const float*)d_in[19];
  const float* bupd = (const float*)d_in[20];
  const float* Wf   = (const float*)d_in[21];
  const float* bf   = (const float*)d_in[22];
  const float* Wf2  = (const float*)d_in[23];
  const float* bf2  = (const float*)d_in[24];
  const float* Wout = (const float*)d_in[25];
  const float* bout = (const float*)d_in[26];

  float* ws    = (float*)d_ws;
  float* ghat  = ws;                             // 128
  uint32_t* pkWf = (uint32_t*)(ws + 128);        // 8192 u32
  uint32_t* pkWu = (uint32_t*)(ws + 8320);       // 6144 u32
  uint32_t* pkWo = (uint32_t*)(ws + 14464);      // 2048 u32
  u64*  bitOp  = (u64*)(ws + 16512);             // 16384 u64 (32768 f32)
  u16*  psumB  = (u16*)(ws + 49280);             // 32768 chunks x 64 u16 (1048576 f32)
  int*  pcntB  = (int*)(ws + 1097856);           // 32768 int
  u16*  psumD  = (u16*)(ws + 1130624);           // 16384 chunks x 64 u16 (524288 f32)
  int*  pcntD  = (int*)(ws + 1654912);           // 16384 int
  u16*  wwkn   = (u16*)(ws + 1671296);           // 524288 u16 (262144 f32)
  u16*  wwsn   = (u16*)(ws + 1933440);           // 524288 u16
  float* WUo   = ws + 2195584;                   // 524288 f32
  u16*  wThi   = (u16*)(ws + 2719872);           // 524288 u16 (262144 f32)
  u16*  wTlo   = (u16*)(ws + 2982016);           // 524288 u16 -> ws end 3244160 f32
  float* out   = (float*)d_out;

  k_prep<<<128, 256, 0, stream>>>(w0, w1, wThi, wTlo);
  k_mask<<<1041, 256, 0, stream>>>(ww, wem, d0, d1, wes, wop, wThi, wTlo,
                                   nh, Wg, bg, Wf, Wupd, Wo,
                                   psumB, pcntB, psumD, pcntD,
                                   bitOp, ghat, pkWf, pkWu, pkWo);
  k_fin<<<1024, 256, 0, stream>>>(psumB, pcntB, psumD, pcntD,
                                  Wwk, bwk, Wws, bws, wwkn, wwsn);
  k_update<<<512, 256, 0, stream>>>(w0, w1, gw, ghat, wwkn, wwsn,
                                    pkWf, pkWu, pkWo, bf, bupd, bo, out, WUo);
  k_opfin<<<256, 256, 0, stream>>>(bitOp, WUo, opE, Wf2, bf2, Wout, bout, out);
}